// Round 1
// baseline (111760.583 us; speedup 1.0000x reference)
//
#include <hip/hip_runtime.h>

#define S_LEN 65536
#define HDIM 128

__device__ __forceinline__ float sigm(float x) {
    return 1.0f / (1.0f + __expf(-x));
}
__device__ __forceinline__ float tanh_fast(float x) {
    // 2/(1+exp(-2x)) - 1 ; saturates correctly for |x| large (exp -> inf / 0)
    return 2.0f / (1.0f + __expf(-2.0f * x)) - 1.0f;
}

__global__ __launch_bounds__(512, 2)
void lstm_seq(const float* __restrict__ x,
              const float* __restrict__ h0,
              const float* __restrict__ c0,
              const float* __restrict__ W_ih,
              const float* __restrict__ W_hh,
              const float* __restrict__ b_ih,
              const float* __restrict__ b_hh,
              const float* __restrict__ W_out,
              const float* __restrict__ b_out,
              float* __restrict__ out)
{
    __shared__ __align__(16) float h_sh[HDIM];
    __shared__ float gates_sh[4 * HDIM];
    __shared__ float red_sh[2];

    const int j = threadIdx.x;  // 0..511 : gate row index (i:0-127, f:128-255, g:256-383, o:384-511)

    // ---- Preload W_hh row j into 128 VGPRs (fully unrolled static indexing) ----
    float w[HDIM];
    {
        const float4* wr = (const float4*)(W_hh + j * HDIM);
        #pragma unroll
        for (int k4 = 0; k4 < HDIM / 4; ++k4) {
            float4 v = wr[k4];
            w[4 * k4 + 0] = v.x;
            w[4 * k4 + 1] = v.y;
            w[4 * k4 + 2] = v.z;
            w[4 * k4 + 3] = v.w;
        }
    }
    const float wih0 = W_ih[2 * j + 0];
    const float wih1 = W_ih[2 * j + 1];
    const float bias = b_ih[j] + b_hh[j];

    float c = 0.0f, wout = 0.0f;
    if (j < HDIM) {
        h_sh[j] = h0[j];
        c = c0[j];
        wout = W_out[j];
    }
    const float bout = b_out[0];
    __syncthreads();

    const float2* xp = (const float2*)x;
    float2 xcur = xp[0];

    #pragma unroll 1
    for (int t = 0; t < S_LEN; ++t) {
        // Prefetch next timestep's input (wave-uniform, L1/L2-cached stream)
        const int tn = (t + 1 < S_LEN) ? (t + 1) : (S_LEN - 1);
        float2 xnext = xp[tn];

        // gates[j] = xg_t[j] + dot(W_hh[j,:], h_{t-1})
        float a0 = fmaf(wih0, xcur.x, fmaf(wih1, xcur.y, bias));
        float a1 = 0.0f, a2 = 0.0f, a3 = 0.0f;
        const float4* h4 = (const float4*)h_sh;
        #pragma unroll
        for (int kc = 0; kc < HDIM / 16; ++kc) {
            float4 hA = h4[4 * kc + 0];
            float4 hB = h4[4 * kc + 1];
            float4 hC = h4[4 * kc + 2];
            float4 hD = h4[4 * kc + 3];
            a0 = fmaf(w[16 * kc +  0], hA.x, a0);
            a0 = fmaf(w[16 * kc +  1], hA.y, a0);
            a0 = fmaf(w[16 * kc +  2], hA.z, a0);
            a0 = fmaf(w[16 * kc +  3], hA.w, a0);
            a1 = fmaf(w[16 * kc +  4], hB.x, a1);
            a1 = fmaf(w[16 * kc +  5], hB.y, a1);
            a1 = fmaf(w[16 * kc +  6], hB.z, a1);
            a1 = fmaf(w[16 * kc +  7], hB.w, a1);
            a2 = fmaf(w[16 * kc +  8], hC.x, a2);
            a2 = fmaf(w[16 * kc +  9], hC.y, a2);
            a2 = fmaf(w[16 * kc + 10], hC.z, a2);
            a2 = fmaf(w[16 * kc + 11], hC.w, a2);
            a3 = fmaf(w[16 * kc + 12], hD.x, a3);
            a3 = fmaf(w[16 * kc + 13], hD.y, a3);
            a3 = fmaf(w[16 * kc + 14], hD.z, a3);
            a3 = fmaf(w[16 * kc + 15], hD.w, a3);
        }
        gates_sh[j] = (a0 + a1) + (a2 + a3);
        __syncthreads();  // barrier 1: gates complete, h_{t-1} no longer needed

        if (j < HDIM) {
            float gi = sigm(gates_sh[j]);
            float gf = sigm(gates_sh[j + HDIM]);
            float gg = tanh_fast(gates_sh[j + 2 * HDIM]);
            float go = sigm(gates_sh[j + 3 * HDIM]);
            c = fmaf(gf, c, gi * gg);
            float h = go * tanh_fast(c);
            h_sh[j] = h;

            // out_t partial: tanh(h) * W_out[j], reduce across 128 lanes (2 waves)
            float partial = tanh_fast(h) * wout;
            #pragma unroll
            for (int off = 32; off > 0; off >>= 1)
                partial += __shfl_xor(partial, off, 64);
            if ((j & 63) == 0) red_sh[j >> 6] = partial;
        }
        __syncthreads();  // barrier 2: h_t visible to all waves

        if (j == 0) out[t] = red_sh[0] + red_sh[1] + bout;

        xcur = xnext;
    }
}

extern "C" void kernel_launch(void* const* d_in, const int* in_sizes, int n_in,
                              void* d_out, int out_size, void* d_ws, size_t ws_size,
                              hipStream_t stream) {
    const float* x     = (const float*)d_in[0];
    const float* h0    = (const float*)d_in[1];
    const float* c0    = (const float*)d_in[2];
    const float* W_ih  = (const float*)d_in[3];
    const float* W_hh  = (const float*)d_in[4];
    const float* b_ih  = (const float*)d_in[5];
    const float* b_hh  = (const float*)d_in[6];
    const float* W_out = (const float*)d_in[7];
    const float* b_out = (const float*)d_in[8];

    lstm_seq<<<dim3(1), dim3(512), 0, stream>>>(
        x, h0, c0, W_ih, W_hh, b_ih, b_hh, W_out, b_out, (float*)d_out);
}

// Round 2
// 102151.196 us; speedup vs baseline: 1.0941x; 1.0941x over previous
//
#include <hip/hip_runtime.h>

#define S_LEN 65536
#define HDIM 128
#define NTHR 1024

__device__ __forceinline__ float sigm(float x) {
    return 1.0f / (1.0f + __expf(-x));
}
__device__ __forceinline__ float tanh_fast(float x) {
    // 2/(1+exp(-2x)) - 1 ; saturates correctly for |x| large
    return 2.0f / (1.0f + __expf(-2.0f * x)) - 1.0f;
}

// 1024 threads = 16 waves on ONE CU. Thread tid: gate row j = tid>>1 (0..511),
// half = tid&1 selects which 64-wide half of the dot product it owns.
// 64 weight VGPRs/thread (vs 128 in R1, which spilled: VGPR_Count=88 < 128).
// __launch_bounds__(1024,4) -> 128 VGPR cap; ~95 needed -> guaranteed resident.
__global__ __launch_bounds__(NTHR, 4)
void lstm_seq(const float* __restrict__ x,
              const float* __restrict__ h0,
              const float* __restrict__ c0,
              const float* __restrict__ W_ih,
              const float* __restrict__ W_hh,
              const float* __restrict__ b_ih,
              const float* __restrict__ b_hh,
              const float* __restrict__ W_out,
              const float* __restrict__ b_out,
              float* __restrict__ out)
{
    __shared__ __align__(16) float h_sh[HDIM];
    __shared__ float gates_sh[4 * HDIM];
    __shared__ float red_sh[2];

    const int tid  = threadIdx.x;
    const int j    = tid >> 1;   // gate row: i:0-127, f:128-255, g:256-383, o:384-511
    const int half = tid & 1;    // which 64 of the 128 k-terms

    // ---- Preload half of W_hh row j into 64 VGPRs (fully unrolled, static) ----
    float w[64];
    {
        const float4* wr = (const float4*)(W_hh + j * HDIM + half * 64);
        #pragma unroll
        for (int k4 = 0; k4 < 16; ++k4) {
            float4 v = wr[k4];
            w[4 * k4 + 0] = v.x;
            w[4 * k4 + 1] = v.y;
            w[4 * k4 + 2] = v.z;
            w[4 * k4 + 3] = v.w;
        }
    }
    // xg + bias contributed only by half==0 (half==1 starts at 0)
    float wih0 = 0.0f, wih1 = 0.0f, bias = 0.0f;
    if (half == 0) {
        wih0 = W_ih[2 * j + 0];
        wih1 = W_ih[2 * j + 1];
        bias = b_ih[j] + b_hh[j];
    }

    float c = 0.0f, wout = 0.0f;
    if (tid < HDIM) {
        h_sh[tid] = h0[tid];
        c = c0[tid];
        wout = W_out[tid];
    }
    const float bout = b_out[0];
    __syncthreads();

    const float2* xp = (const float2*)x;
    float2 xcur = xp[0];

    #pragma unroll 1
    for (int t = 0; t < S_LEN; ++t) {
        const int tn = (t + 1 < S_LEN) ? (t + 1) : (S_LEN - 1);
        float2 xnext = xp[tn];  // prefetch next input (wave-uniform stream)

        // partial dot over 64 terms, 4 independent accumulators
        float a0 = fmaf(wih0, xcur.x, fmaf(wih1, xcur.y, bias));
        float a1 = 0.0f, a2 = 0.0f, a3 = 0.0f;
        const float4* h4 = (const float4*)(h_sh + half * 64);
        #pragma unroll
        for (int kc = 0; kc < 4; ++kc) {   // 4 x 16 terms
            float4 hA = h4[4 * kc + 0];
            float4 hB = h4[4 * kc + 1];
            float4 hC = h4[4 * kc + 2];
            float4 hD = h4[4 * kc + 3];
            a0 = fmaf(w[16 * kc +  0], hA.x, a0);
            a0 = fmaf(w[16 * kc +  1], hA.y, a0);
            a0 = fmaf(w[16 * kc +  2], hA.z, a0);
            a0 = fmaf(w[16 * kc +  3], hA.w, a0);
            a1 = fmaf(w[16 * kc +  4], hB.x, a1);
            a1 = fmaf(w[16 * kc +  5], hB.y, a1);
            a1 = fmaf(w[16 * kc +  6], hB.z, a1);
            a1 = fmaf(w[16 * kc +  7], hB.w, a1);
            a2 = fmaf(w[16 * kc +  8], hC.x, a2);
            a2 = fmaf(w[16 * kc +  9], hC.y, a2);
            a2 = fmaf(w[16 * kc + 10], hC.z, a2);
            a2 = fmaf(w[16 * kc + 11], hC.w, a2);
            a3 = fmaf(w[16 * kc + 12], hD.x, a3);
            a3 = fmaf(w[16 * kc + 13], hD.y, a3);
            a3 = fmaf(w[16 * kc + 14], hD.z, a3);
            a3 = fmaf(w[16 * kc + 15], hD.w, a3);
        }
        float partial = (a0 + a1) + (a2 + a3);
        // combine the two halves: pair (2j, 2j+1) are adjacent lanes of one wave
        partial += __shfl_xor(partial, 1, 64);
        if (half == 0) gates_sh[j] = partial;
        __syncthreads();  // barrier 1: gates complete; h_{t-1} free to overwrite

        if (tid < HDIM) {
            float gi = sigm(gates_sh[tid]);
            float gf = sigm(gates_sh[tid + HDIM]);
            float gg = tanh_fast(gates_sh[tid + 2 * HDIM]);
            float go = sigm(gates_sh[tid + 3 * HDIM]);
            c = fmaf(gf, c, gi * gg);
            float h = go * tanh_fast(c);
            h_sh[tid] = h;

            // out_t = sum tanh(h)*W_out : reduce over 128 lanes (2 waves)
            float p = tanh_fast(h) * wout;
            #pragma unroll
            for (int off = 32; off > 0; off >>= 1)
                p += __shfl_xor(p, off, 64);
            if ((tid & 63) == 0) red_sh[tid >> 6] = p;
        }
        __syncthreads();  // barrier 2: h_t visible to all waves

        if (tid == 0) out[t] = red_sh[0] + red_sh[1] + bout;

        xcur = xnext;
    }
}

extern "C" void kernel_launch(void* const* d_in, const int* in_sizes, int n_in,
                              void* d_out, int out_size, void* d_ws, size_t ws_size,
                              hipStream_t stream) {
    const float* x     = (const float*)d_in[0];
    const float* h0    = (const float*)d_in[1];
    const float* c0    = (const float*)d_in[2];
    const float* W_ih  = (const float*)d_in[3];
    const float* W_hh  = (const float*)d_in[4];
    const float* b_ih  = (const float*)d_in[5];
    const float* b_hh  = (const float*)d_in[6];
    const float* W_out = (const float*)d_in[7];
    const float* b_out = (const float*)d_in[8];

    lstm_seq<<<dim3(1), dim3(NTHR), 0, stream>>>(
        x, h0, c0, W_ih, W_hh, b_ih, b_hh, W_out, b_out, (float*)d_out);
}

// Round 3
// 73541.931 us; speedup vs baseline: 1.5197x; 1.3890x over previous
//
#include <hip/hip_runtime.h>

#define S_LEN 65536
#define HDIM 128
#define NTHR 1024

__device__ __forceinline__ float sigm(float x) {
    return 1.0f / (1.0f + __expf(-x));
}
__device__ __forceinline__ float tanh_fast(float x) {
    return 2.0f / (1.0f + __expf(-2.0f * x)) - 1.0f;
}

// 1024 threads = 16 waves, one CU. tid -> (row j = tid>>1, half = tid&1).
// Weights: 16 NAMED float4 vars (64 floats) -> pure SSA, cannot be
// scratch-demoted (R1/R2 showed float w[N] arrays spill: VGPR_Count 88/48).
// h layout: lo half at float-offset 0, hi half at float-offset 68
// (byte 272 == 16 mod 128) -> even-lane banks {4kc..4kc+3}, odd-lane
// banks {4kc+4..4kc+7}: disjoint, broadcast, zero conflicts
// (R2: SQ_LDS_BANK_CONFLICT=6.7e7 from the unskewed A/A+256B split).
#define H_SKEW 68

__global__ __launch_bounds__(NTHR, 4)
void lstm_seq(const float* __restrict__ x,
              const float* __restrict__ h0,
              const float* __restrict__ c0,
              const float* __restrict__ W_ih,
              const float* __restrict__ W_hh,
              const float* __restrict__ b_ih,
              const float* __restrict__ b_hh,
              const float* __restrict__ W_out,
              const float* __restrict__ b_out,
              float* __restrict__ out)
{
    __shared__ __align__(16) float h_sh[2 * H_SKEW];   // [0..63] lo, [68..131] hi
    __shared__ float gates_sh[4 * HDIM];
    __shared__ float red_sh[2];

    const int tid  = threadIdx.x;
    const int j    = tid >> 1;   // gate row: i:0-127, f:128-255, g:256-383, o:384-511
    const int half = tid & 1;

    const float4* wr = (const float4*)(W_hh + j * HDIM + half * 64);
    float4 w0  = wr[0],  w1  = wr[1],  w2  = wr[2],  w3  = wr[3];
    float4 w4  = wr[4],  w5  = wr[5],  w6  = wr[6],  w7  = wr[7];
    float4 w8  = wr[8],  w9  = wr[9],  w10 = wr[10], w11 = wr[11];
    float4 w12 = wr[12], w13 = wr[13], w14 = wr[14], w15 = wr[15];

    float wih0 = 0.0f, wih1 = 0.0f, bias = 0.0f;
    if (half == 0) {
        wih0 = W_ih[2 * j + 0];
        wih1 = W_ih[2 * j + 1];
        bias = b_ih[j] + b_hh[j];
    }

    float c = 0.0f, wout = 0.0f;
    if (tid < HDIM) {
        h_sh[tid + ((tid >= 64) ? (H_SKEW - 64) : 0)] = h0[tid];
        c = c0[tid];
        wout = W_out[tid];
    }
    const float bout = b_out[0];
    __syncthreads();

    const float2* xp = (const float2*)x;
    float2 xcur = xp[0];

    #pragma unroll 1
    for (int t = 0; t < S_LEN; ++t) {
        const int tn = (t + 1 < S_LEN) ? (t + 1) : (S_LEN - 1);
        float2 xnext = xp[tn];  // prefetch next input (wave-uniform stream)

        float a0 = fmaf(wih0, xcur.x, fmaf(wih1, xcur.y, bias));
        float a1 = 0.0f, a2 = 0.0f, a3 = 0.0f;
        const float4* h4 = (const float4*)(h_sh + half * H_SKEW);

        #define FMA4(kc, acc) { float4 hv = h4[kc];            \
            acc = fmaf(w##kc.x, hv.x, acc);                    \
            acc = fmaf(w##kc.y, hv.y, acc);                    \
            acc = fmaf(w##kc.z, hv.z, acc);                    \
            acc = fmaf(w##kc.w, hv.w, acc); }
        FMA4(0,  a0) FMA4(1,  a1) FMA4(2,  a2) FMA4(3,  a3)
        FMA4(4,  a0) FMA4(5,  a1) FMA4(6,  a2) FMA4(7,  a3)
        FMA4(8,  a0) FMA4(9,  a1) FMA4(10, a2) FMA4(11, a3)
        FMA4(12, a0) FMA4(13, a1) FMA4(14, a2) FMA4(15, a3)
        #undef FMA4

        float partial = (a0 + a1) + (a2 + a3);
        partial += __shfl_xor(partial, 1, 64);   // pair (2j,2j+1) adjacent lanes
        if (half == 0) gates_sh[j] = partial;
        __syncthreads();  // barrier 1: gates done; h_{t-1} dead

        if (tid < HDIM) {
            float gi = sigm(gates_sh[tid]);
            float gf = sigm(gates_sh[tid + HDIM]);
            float gg = tanh_fast(gates_sh[tid + 2 * HDIM]);
            float go = sigm(gates_sh[tid + 3 * HDIM]);
            c = fmaf(gf, c, gi * gg);
            float h = go * tanh_fast(c);
            h_sh[tid + ((tid >= 64) ? (H_SKEW - 64) : 0)] = h;

            float p = tanh_fast(h) * wout;
            #pragma unroll
            for (int off = 32; off > 0; off >>= 1)
                p += __shfl_xor(p, off, 64);
            if ((tid & 63) == 0) red_sh[tid >> 6] = p;
        }
        __syncthreads();  // barrier 2: h_t visible

        if (tid == 0) out[t] = red_sh[0] + red_sh[1] + bout;

        xcur = xnext;
    }
}

extern "C" void kernel_launch(void* const* d_in, const int* in_sizes, int n_in,
                              void* d_out, int out_size, void* d_ws, size_t ws_size,
                              hipStream_t stream) {
    const float* x     = (const float*)d_in[0];
    const float* h0    = (const float*)d_in[1];
    const float* c0    = (const float*)d_in[2];
    const float* W_ih  = (const float*)d_in[3];
    const float* W_hh  = (const float*)d_in[4];
    const float* b_ih  = (const float*)d_in[5];
    const float* b_hh  = (const float*)d_in[6];
    const float* W_out = (const float*)d_in[7];
    const float* b_out = (const float*)d_in[8];

    lstm_seq<<<dim3(1), dim3(NTHR), 0, stream>>>(
        x, h0, c0, W_ih, W_hh, b_ih, b_hh, W_out, b_out, (float*)d_out);
}

// Round 4
// 65035.175 us; speedup vs baseline: 1.7185x; 1.1308x over previous
//
#include <hip/hip_runtime.h>

#define S_LEN 65536
#define HDIM 128
#define NTHR 1024

typedef _Float16 half2_t __attribute__((ext_vector_type(2)));
typedef _Float16 half8_t __attribute__((ext_vector_type(8)));

__device__ __forceinline__ float sigm(float x) {
    return 1.0f / (1.0f + __expf(-x));
}
__device__ __forceinline__ float tanh_fast(float x) {
    return 2.0f / (1.0f + __expf(-2.0f * x)) - 1.0f;
}

__device__ __forceinline__ float dot2(half2_t a, half2_t b, float c) {
#if __has_builtin(__builtin_amdgcn_fdot2)
    return __builtin_amdgcn_fdot2(a, b, c, false);
#else
    return fmaf((float)a.x, (float)b.x, fmaf((float)a.y, (float)b.y, c));
#endif
}

// 1024 threads = 16 waves, one CU. tid -> (row j = tid>>1, half = tid&1).
//
// R1-R3 lesson: the allocator refuses to keep >~48 VGPRs of loop-invariant
// loaded data live; it sinks the loads into the loop (VGPR_Count stayed 48,
// ~2640 cyc/step of L1 reload issue). Fix: weights as 32 PACKED f16 dwords
// (fits the comfort zone) AND inline-asm pinned -> opaque asm defs, cannot
// be rematerialized from memory.
//
// h lives in LDS as packed f16: lo half bytes [0,128), hi half at byte 144
// (144 % 128 == 16 -> even-lane banks {4k..4k+3}, odd-lane {4k+4..4k+7},
// disjoint -> conflict-free broadcast reads; 144 % 16 == 0 keeps b128 align).
#define H_HI_OFF 144

__global__ __launch_bounds__(NTHR, 4)
void lstm_seq(const float* __restrict__ x,
              const float* __restrict__ h0,
              const float* __restrict__ c0,
              const float* __restrict__ W_ih,
              const float* __restrict__ W_hh,
              const float* __restrict__ b_ih,
              const float* __restrict__ b_hh,
              const float* __restrict__ W_out,
              const float* __restrict__ b_out,
              float* __restrict__ out)
{
    __shared__ __align__(16) unsigned char h_raw[2 * H_HI_OFF];
    __shared__ float gates_sh[4 * HDIM];
    __shared__ float red_sh[2];

    const int tid  = threadIdx.x;
    const int j    = tid >> 1;   // gate row: i:0-127, f:128-255, g:256-383, o:384-511
    const int half = tid & 1;

    // ---- Convert this thread's 64 weights to 32 packed f16 dwords, pin. ----
    const float2* wr2 = (const float2*)(W_hh + j * HDIM + half * 64);
#define WDEF(i) half2_t W##i; { float2 t = wr2[i]; \
        W##i.x = (_Float16)t.x; W##i.y = (_Float16)t.y; } \
        asm volatile("" : "+v"(W##i));
    WDEF(0)  WDEF(1)  WDEF(2)  WDEF(3)  WDEF(4)  WDEF(5)  WDEF(6)  WDEF(7)
    WDEF(8)  WDEF(9)  WDEF(10) WDEF(11) WDEF(12) WDEF(13) WDEF(14) WDEF(15)
    WDEF(16) WDEF(17) WDEF(18) WDEF(19) WDEF(20) WDEF(21) WDEF(22) WDEF(23)
    WDEF(24) WDEF(25) WDEF(26) WDEF(27) WDEF(28) WDEF(29) WDEF(30) WDEF(31)
#undef WDEF

    float wih0 = 0.0f, wih1 = 0.0f, bias = 0.0f;
    if (half == 0) {
        wih0 = W_ih[2 * j + 0];
        wih1 = W_ih[2 * j + 1];
        bias = b_ih[j] + b_hh[j];
    }

    float c = 0.0f, wout = 0.0f;
    _Float16* hw = (_Float16*)(h_raw + ((tid < 64) ? 2 * tid
                                                   : H_HI_OFF + 2 * (tid - 64)));
    if (tid < HDIM) {
        c = c0[tid];
        wout = W_out[tid];
        *hw = (_Float16)h0[tid];
    }
    const float bout = b_out[0];
    __syncthreads();

    const float2* xp = (const float2*)x;
    float2 xcur = xp[0];
    const half8_t* hp = (const half8_t*)(h_raw + half * H_HI_OFF);

    #pragma unroll 1
    for (int t = 0; t < S_LEN; ++t) {
        const int tn = (t + 1 < S_LEN) ? (t + 1) : (S_LEN - 1);
        float2 xnext = xp[tn];  // prefetch next input (wave-uniform stream)

        float a0 = fmaf(wih0, xcur.x, fmaf(wih1, xcur.y, bias));
        float a1 = 0.0f, a2 = 0.0f, a3 = 0.0f;

        // 8 chunks x (1 ds_read_b128 + 4 dot2). Broadcast reads: even lanes
        // one address, odd lanes one address, disjoint bank groups.
#define CHUNK(cc, w0_, w1_, w2_, w3_) {                         \
        half8_t hv = hp[cc];                                    \
        half2_t p0 = { hv[0], hv[1] };                          \
        half2_t p1 = { hv[2], hv[3] };                          \
        half2_t p2 = { hv[4], hv[5] };                          \
        half2_t p3 = { hv[6], hv[7] };                          \
        a0 = dot2(w0_, p0, a0);                                 \
        a1 = dot2(w1_, p1, a1);                                 \
        a2 = dot2(w2_, p2, a2);                                 \
        a3 = dot2(w3_, p3, a3); }
        CHUNK(0, W0,  W1,  W2,  W3)
        CHUNK(1, W4,  W5,  W6,  W7)
        CHUNK(2, W8,  W9,  W10, W11)
        CHUNK(3, W12, W13, W14, W15)
        CHUNK(4, W16, W17, W18, W19)
        CHUNK(5, W20, W21, W22, W23)
        CHUNK(6, W24, W25, W26, W27)
        CHUNK(7, W28, W29, W30, W31)
#undef CHUNK

        float partial = (a0 + a1) + (a2 + a3);
        partial += __shfl_xor(partial, 1, 64);   // pair (2j,2j+1) adjacent lanes
        if (half == 0) gates_sh[j] = partial;
        __syncthreads();  // barrier 1: gates done; h_{t-1} dead

        if (tid < HDIM) {
            float gi = sigm(gates_sh[tid]);
            float gf = sigm(gates_sh[tid + HDIM]);
            float gg = tanh_fast(gates_sh[tid + 2 * HDIM]);
            float go = sigm(gates_sh[tid + 3 * HDIM]);
            c = fmaf(gf, c, gi * gg);
            float h = go * tanh_fast(c);
            *hw = (_Float16)h;   // packed f16 h for next step's dot2

            float p = tanh_fast(h) * wout;
            #pragma unroll
            for (int off = 32; off > 0; off >>= 1)
                p += __shfl_xor(p, off, 64);
            if ((tid & 63) == 0) red_sh[tid >> 6] = p;
        }
        __syncthreads();  // barrier 2: h_t visible

        if (tid == 0) out[t] = red_sh[0] + red_sh[1] + bout;

        xcur = xnext;
    }
}

extern "C" void kernel_launch(void* const* d_in, const int* in_sizes, int n_in,
                              void* d_out, int out_size, void* d_ws, size_t ws_size,
                              hipStream_t stream) {
    const float* x     = (const float*)d_in[0];
    const float* h0    = (const float*)d_in[1];
    const float* c0    = (const float*)d_in[2];
    const float* W_ih  = (const float*)d_in[3];
    const float* W_hh  = (const float*)d_in[4];
    const float* b_ih  = (const float*)d_in[5];
    const float* b_hh  = (const float*)d_in[6];
    const float* W_out = (const float*)d_in[7];
    const float* b_out = (const float*)d_in[8];

    lstm_seq<<<dim3(1), dim3(NTHR), 0, stream>>>(
        x, h0, c0, W_ih, W_hh, b_ih, b_hh, W_out, b_out, (float*)d_out);
}

// Round 5
// 62813.837 us; speedup vs baseline: 1.7792x; 1.0354x over previous
//
#include <hip/hip_runtime.h>

#define S_LEN 65536
#define HDIM 128
#define NTHR 1024

typedef _Float16 half2_t __attribute__((ext_vector_type(2)));
typedef _Float16 half8_t __attribute__((ext_vector_type(8)));

__device__ __forceinline__ float sigm(float x) {
    return 1.0f / (1.0f + __expf(-x));
}
__device__ __forceinline__ float tanh_fast(float x) {
    return 2.0f / (1.0f + __expf(-2.0f * x)) - 1.0f;
}

__device__ __forceinline__ float dot2(half2_t a, half2_t b, float c) {
#if __has_builtin(__builtin_amdgcn_fdot2)
    return __builtin_amdgcn_fdot2(a, b, c, false);
#else
    return fmaf((float)a.x, (float)b.x, fmaf((float)a.y, (float)b.y, c));
#endif
}

// 1024 threads = 16 waves, one CU. tid -> (row j = tid>>1, half = tid&1).
//
// R1-R4 root cause: __launch_bounds__(N, 4) sets only the MIN waves/EU; the
// GCN scheduler's occupancy stage still targets 8 waves/EU (it can't see that
// the grid is a single block), so its remat/spill stages crush VGPR pressure
// to 36-48 regs and reload the weights from scratch every iteration
// (~2300-2600 cyc/step). amdgpu_waves_per_eu(4,4) pins min=max=4 -> a
// 128-VGPR allocation is acceptable -> the 32 packed-f16 weight dwords
// (asm-pinned, so also un-rematerializable) stay resident.
//
// h lives in LDS as packed f16: lo half bytes [0,128), hi half at byte 144
// (144 % 128 == 16 -> even-lane banks {4k..4k+3}, odd-lane {4k+4..4k+7},
// disjoint -> conflict-free broadcast; 144 % 16 == 0 keeps b128 alignment).
#define H_HI_OFF 144

__global__ __launch_bounds__(NTHR)
__attribute__((amdgpu_waves_per_eu(4, 4)))
void lstm_seq(const float* __restrict__ x,
              const float* __restrict__ h0,
              const float* __restrict__ c0,
              const float* __restrict__ W_ih,
              const float* __restrict__ W_hh,
              const float* __restrict__ b_ih,
              const float* __restrict__ b_hh,
              const float* __restrict__ W_out,
              const float* __restrict__ b_out,
              float* __restrict__ out)
{
    __shared__ __align__(16) unsigned char h_raw[2 * H_HI_OFF];
    __shared__ float gates_sh[4 * HDIM];
    __shared__ float red_sh[2];

    const int tid  = threadIdx.x;
    const int j    = tid >> 1;   // gate row: i:0-127, f:128-255, g:256-383, o:384-511
    const int half = tid & 1;

    // ---- This thread's 64 weights as 32 packed f16 dwords, asm-pinned. ----
    const float2* wr2 = (const float2*)(W_hh + j * HDIM + half * 64);
#define WDEF(i) half2_t W##i; { float2 t = wr2[i]; \
        W##i.x = (_Float16)t.x; W##i.y = (_Float16)t.y; } \
        asm volatile("" : "+v"(W##i));
    WDEF(0)  WDEF(1)  WDEF(2)  WDEF(3)  WDEF(4)  WDEF(5)  WDEF(6)  WDEF(7)
    WDEF(8)  WDEF(9)  WDEF(10) WDEF(11) WDEF(12) WDEF(13) WDEF(14) WDEF(15)
    WDEF(16) WDEF(17) WDEF(18) WDEF(19) WDEF(20) WDEF(21) WDEF(22) WDEF(23)
    WDEF(24) WDEF(25) WDEF(26) WDEF(27) WDEF(28) WDEF(29) WDEF(30) WDEF(31)
#undef WDEF

    float wih0 = 0.0f, wih1 = 0.0f, bias = 0.0f;
    if (half == 0) {
        wih0 = W_ih[2 * j + 0];
        wih1 = W_ih[2 * j + 1];
        bias = b_ih[j] + b_hh[j];
    }

    float c = 0.0f, wout = 0.0f;
    _Float16* hw = (_Float16*)(h_raw + ((tid < 64) ? 2 * tid
                                                   : H_HI_OFF + 2 * (tid - 64)));
    if (tid < HDIM) {
        c = c0[tid];
        wout = W_out[tid];
        *hw = (_Float16)h0[tid];
    }
    const float bout = b_out[0];
    __syncthreads();

    const float2* xp = (const float2*)x;
    float2 xcur = xp[0];
    const half8_t* hp = (const half8_t*)(h_raw + half * H_HI_OFF);

    #pragma unroll 1
    for (int t = 0; t < S_LEN; ++t) {
        const int tn = (t + 1 < S_LEN) ? (t + 1) : (S_LEN - 1);
        float2 xnext = xp[tn];  // prefetch next input (wave-uniform stream)

        float a0 = fmaf(wih0, xcur.x, fmaf(wih1, xcur.y, bias));
        float a1 = 0.0f, a2 = 0.0f, a3 = 0.0f;

        // 8 chunks x (1 ds_read_b128 + 4 v_dot2_f32_f16), 4 indep acc chains.
#define CHUNK(cc, w0_, w1_, w2_, w3_) {                         \
        half8_t hv = hp[cc];                                    \
        half2_t p0 = { hv[0], hv[1] };                          \
        half2_t p1 = { hv[2], hv[3] };                          \
        half2_t p2 = { hv[4], hv[5] };                          \
        half2_t p3 = { hv[6], hv[7] };                          \
        a0 = dot2(w0_, p0, a0);                                 \
        a1 = dot2(w1_, p1, a1);                                 \
        a2 = dot2(w2_, p2, a2);                                 \
        a3 = dot2(w3_, p3, a3); }
        CHUNK(0, W0,  W1,  W2,  W3)
        CHUNK(1, W4,  W5,  W6,  W7)
        CHUNK(2, W8,  W9,  W10, W11)
        CHUNK(3, W12, W13, W14, W15)
        CHUNK(4, W16, W17, W18, W19)
        CHUNK(5, W20, W21, W22, W23)
        CHUNK(6, W24, W25, W26, W27)
        CHUNK(7, W28, W29, W30, W31)
#undef CHUNK

        float partial = (a0 + a1) + (a2 + a3);
        partial += __shfl_xor(partial, 1, 64);   // pair (2j,2j+1) adjacent lanes
        if (half == 0) gates_sh[j] = partial;
        __syncthreads();  // barrier 1: gates done; h_{t-1} dead

        if (tid < HDIM) {
            float gi = sigm(gates_sh[tid]);
            float gf = sigm(gates_sh[tid + HDIM]);
            float gg = tanh_fast(gates_sh[tid + 2 * HDIM]);
            float go = sigm(gates_sh[tid + 3 * HDIM]);
            c = fmaf(gf, c, gi * gg);
            float h = go * tanh_fast(c);
            *hw = (_Float16)h;   // packed f16 h for next step's dot2

            float p = tanh_fast(h) * wout;
            #pragma unroll
            for (int off = 32; off > 0; off >>= 1)
                p += __shfl_xor(p, off, 64);
            if ((tid & 63) == 0) red_sh[tid >> 6] = p;
        }
        __syncthreads();  // barrier 2: h_t visible

        if (tid == 0) out[t] = red_sh[0] + red_sh[1] + bout;

        xcur = xnext;
    }
}

extern "C" void kernel_launch(void* const* d_in, const int* in_sizes, int n_in,
                              void* d_out, int out_size, void* d_ws, size_t ws_size,
                              hipStream_t stream) {
    const float* x     = (const float*)d_in[0];
    const float* h0    = (const float*)d_in[1];
    const float* c0    = (const float*)d_in[2];
    const float* W_ih  = (const float*)d_in[3];
    const float* W_hh  = (const float*)d_in[4];
    const float* b_ih  = (const float*)d_in[5];
    const float* b_hh  = (const float*)d_in[6];
    const float* W_out = (const float*)d_in[7];
    const float* b_out = (const float*)d_in[8];

    lstm_seq<<<dim3(1), dim3(NTHR), 0, stream>>>(
        x, h0, c0, W_ih, W_hh, b_ih, b_hh, W_out, b_out, (float*)d_out);
}

// Round 6
// 45947.406 us; speedup vs baseline: 2.4324x; 1.3671x over previous
//
#include <hip/hip_runtime.h>

#define S_LEN 65536
#define HDIM 128
#define NTHR 1024

typedef _Float16 half2_t __attribute__((ext_vector_type(2)));
typedef _Float16 half8_t __attribute__((ext_vector_type(8)));

__device__ __forceinline__ float sigm(float x) {
    return 1.0f / (1.0f + __expf(-x));
}
__device__ __forceinline__ float tanh_fast(float x) {
    return 2.0f / (1.0f + __expf(-2.0f * x)) - 1.0f;
}

__device__ __forceinline__ float dot2(half2_t a, half2_t b, float c) {
#if __has_builtin(__builtin_amdgcn_fdot2)
    return __builtin_amdgcn_fdot2(a, b, c, false);
#else
    return fmaf((float)a.x, (float)b.x, fmaf((float)a.y, (float)b.y, c));
#endif
}

// h LDS layout: lo half bytes [0,128), hi half at byte 144 (16 mod 128 ->
// even-lane/odd-lane bank groups disjoint -> conflict-free broadcast).
#define H_HI_OFF 144

// ---------------- Kernel 1: sequential recurrence, h history out ----------
// R5 post-mortem: ~half of the 2330 cyc/step was the serial out[t] tail
// (6 dependent ds_swizzle stages ~700 cyc + epilogue). Moved to kernel 2.
// Gate half-combine shuffle also removed: both halves write partials to LDS,
// phase B adds them (batched read, no dependent swizzle).
__global__ __launch_bounds__(NTHR)
__attribute__((amdgpu_waves_per_eu(4, 4)))
void lstm_seq_h(const float* __restrict__ x,
                const float* __restrict__ h0,
                const float* __restrict__ c0,
                const float* __restrict__ W_ih,
                const float* __restrict__ W_hh,
                const float* __restrict__ b_ih,
                const float* __restrict__ b_hh,
                _Float16* __restrict__ h_hist)
{
    __shared__ __align__(16) unsigned char h_raw[2 * H_HI_OFF];
    __shared__ float gates_part[2 * 512];   // [half][row]

    const int tid  = threadIdx.x;
    const int j    = tid >> 1;   // gate row: i:0-127, f:128-255, g:256-383, o:384-511
    const int half = tid & 1;

    const float2* wr2 = (const float2*)(W_hh + j * HDIM + half * 64);
#define WDEF(i) half2_t W##i; { float2 t = wr2[i]; \
        W##i.x = (_Float16)t.x; W##i.y = (_Float16)t.y; } \
        asm volatile("" : "+v"(W##i));
    WDEF(0)  WDEF(1)  WDEF(2)  WDEF(3)  WDEF(4)  WDEF(5)  WDEF(6)  WDEF(7)
    WDEF(8)  WDEF(9)  WDEF(10) WDEF(11) WDEF(12) WDEF(13) WDEF(14) WDEF(15)
    WDEF(16) WDEF(17) WDEF(18) WDEF(19) WDEF(20) WDEF(21) WDEF(22) WDEF(23)
    WDEF(24) WDEF(25) WDEF(26) WDEF(27) WDEF(28) WDEF(29) WDEF(30) WDEF(31)
#undef WDEF

    float wih0 = 0.0f, wih1 = 0.0f, bias = 0.0f;
    if (half == 0) {
        wih0 = W_ih[2 * j + 0];
        wih1 = W_ih[2 * j + 1];
        bias = b_ih[j] + b_hh[j];
    }

    float c = 0.0f;
    _Float16* hw = (_Float16*)(h_raw + ((tid < 64) ? 2 * tid
                                                   : H_HI_OFF + 2 * (tid - 64)));
    if (tid < HDIM) {
        c = c0[tid];
        *hw = (_Float16)h0[tid];
    }
    __syncthreads();

    const float2* xp = (const float2*)x;
    float2 xcur = xp[0];
    const half8_t* hp = (const half8_t*)(h_raw + half * H_HI_OFF);

    #pragma unroll 1
    for (int t = 0; t < S_LEN; ++t) {
        const int tn = (t + 1 < S_LEN) ? (t + 1) : (S_LEN - 1);
        float2 xnext = xp[tn];  // prefetch next input (wave-uniform stream)

        float a0 = fmaf(wih0, xcur.x, fmaf(wih1, xcur.y, bias));
        float a1 = 0.0f, a2 = 0.0f, a3 = 0.0f;

#define CHUNK(cc, w0_, w1_, w2_, w3_) {                         \
        half8_t hv = hp[cc];                                    \
        half2_t p0 = { hv[0], hv[1] };                          \
        half2_t p1 = { hv[2], hv[3] };                          \
        half2_t p2 = { hv[4], hv[5] };                          \
        half2_t p3 = { hv[6], hv[7] };                          \
        a0 = dot2(w0_, p0, a0);                                 \
        a1 = dot2(w1_, p1, a1);                                 \
        a2 = dot2(w2_, p2, a2);                                 \
        a3 = dot2(w3_, p3, a3); }
        CHUNK(0, W0,  W1,  W2,  W3)
        CHUNK(1, W4,  W5,  W6,  W7)
        CHUNK(2, W8,  W9,  W10, W11)
        CHUNK(3, W12, W13, W14, W15)
        CHUNK(4, W16, W17, W18, W19)
        CHUNK(5, W20, W21, W22, W23)
        CHUNK(6, W24, W25, W26, W27)
        CHUNK(7, W28, W29, W30, W31)
#undef CHUNK

        // no shuffle: each half writes its partial (conflict-free pattern)
        gates_part[half * 512 + j] = (a0 + a1) + (a2 + a3);
        __syncthreads();  // barrier 1: partials done; h_{t-1} dead

        if (tid < HDIM) {
            float gi = sigm(gates_part[tid]           + gates_part[tid + 512]);
            float gf = sigm(gates_part[tid + 128]     + gates_part[tid + 640]);
            float gg = tanh_fast(gates_part[tid + 256] + gates_part[tid + 768]);
            float go = sigm(gates_part[tid + 384]     + gates_part[tid + 896]);
            c = fmaf(gf, c, gi * gg);
            float h = go * tanh_fast(c);
            _Float16 hf = (_Float16)h;
            *hw = hf;                          // LDS: feeds next step's dot
            h_hist[t * HDIM + tid] = hf;       // global: consumed by out_proj
        }
        __syncthreads();  // barrier 2: h_t visible

        xcur = xnext;
    }
}

// ---------------- Kernel 2: out[t] = tanh(h_t) . W_out + b (parallel) -----
__global__ __launch_bounds__(256)
void out_proj(const _Float16* __restrict__ h_hist,
              const float* __restrict__ W_out,
              const float* __restrict__ b_out,
              float* __restrict__ out)
{
    const int lane  = threadIdx.x & 63;
    const int gwave = (blockIdx.x * 256 + threadIdx.x) >> 6;
    const int nwave = (gridDim.x * 256) >> 6;

    const float wo0 = W_out[2 * lane + 0];
    const float wo1 = W_out[2 * lane + 1];
    const float bout = b_out[0];

    for (int t = gwave; t < S_LEN; t += nwave) {
        half2_t hv = ((const half2_t*)(h_hist + t * HDIM))[lane];
        float p = tanh_fast((float)hv.x) * wo0 + tanh_fast((float)hv.y) * wo1;
        #pragma unroll
        for (int off = 32; off > 0; off >>= 1)
            p += __shfl_xor(p, off, 64);
        if (lane == 0) out[t] = p + bout;
    }
}

// ---------------- Fallback: fused single kernel (if ws too small) ---------
__global__ __launch_bounds__(NTHR)
__attribute__((amdgpu_waves_per_eu(4, 4)))
void lstm_seq_full(const float* __restrict__ x,
                   const float* __restrict__ h0,
                   const float* __restrict__ c0,
                   const float* __restrict__ W_ih,
                   const float* __restrict__ W_hh,
                   const float* __restrict__ b_ih,
                   const float* __restrict__ b_hh,
                   const float* __restrict__ W_out,
                   const float* __restrict__ b_out,
                   float* __restrict__ out)
{
    __shared__ __align__(16) unsigned char h_raw[2 * H_HI_OFF];
    __shared__ float gates_part[2 * 512];
    __shared__ float red_sh[2];

    const int tid  = threadIdx.x;
    const int j    = tid >> 1;
    const int half = tid & 1;

    const float2* wr2 = (const float2*)(W_hh + j * HDIM + half * 64);
#define WDEF(i) half2_t W##i; { float2 t = wr2[i]; \
        W##i.x = (_Float16)t.x; W##i.y = (_Float16)t.y; } \
        asm volatile("" : "+v"(W##i));
    WDEF(0)  WDEF(1)  WDEF(2)  WDEF(3)  WDEF(4)  WDEF(5)  WDEF(6)  WDEF(7)
    WDEF(8)  WDEF(9)  WDEF(10) WDEF(11) WDEF(12) WDEF(13) WDEF(14) WDEF(15)
    WDEF(16) WDEF(17) WDEF(18) WDEF(19) WDEF(20) WDEF(21) WDEF(22) WDEF(23)
    WDEF(24) WDEF(25) WDEF(26) WDEF(27) WDEF(28) WDEF(29) WDEF(30) WDEF(31)
#undef WDEF

    float wih0 = 0.0f, wih1 = 0.0f, bias = 0.0f;
    if (half == 0) {
        wih0 = W_ih[2 * j + 0];
        wih1 = W_ih[2 * j + 1];
        bias = b_ih[j] + b_hh[j];
    }

    float c = 0.0f, wout = 0.0f;
    _Float16* hw = (_Float16*)(h_raw + ((tid < 64) ? 2 * tid
                                                   : H_HI_OFF + 2 * (tid - 64)));
    if (tid < HDIM) {
        c = c0[tid];
        wout = W_out[tid];
        *hw = (_Float16)h0[tid];
    }
    const float bout = b_out[0];
    __syncthreads();

    const float2* xp = (const float2*)x;
    float2 xcur = xp[0];
    const half8_t* hp = (const half8_t*)(h_raw + half * H_HI_OFF);

    #pragma unroll 1
    for (int t = 0; t < S_LEN; ++t) {
        const int tn = (t + 1 < S_LEN) ? (t + 1) : (S_LEN - 1);
        float2 xnext = xp[tn];

        float a0 = fmaf(wih0, xcur.x, fmaf(wih1, xcur.y, bias));
        float a1 = 0.0f, a2 = 0.0f, a3 = 0.0f;

#define CHUNK(cc, w0_, w1_, w2_, w3_) {                         \
        half8_t hv = hp[cc];                                    \
        half2_t p0 = { hv[0], hv[1] };                          \
        half2_t p1 = { hv[2], hv[3] };                          \
        half2_t p2 = { hv[4], hv[5] };                          \
        half2_t p3 = { hv[6], hv[7] };                          \
        a0 = dot2(w0_, p0, a0);                                 \
        a1 = dot2(w1_, p1, a1);                                 \
        a2 = dot2(w2_, p2, a2);                                 \
        a3 = dot2(w3_, p3, a3); }
        CHUNK(0, W0,  W1,  W2,  W3)
        CHUNK(1, W4,  W5,  W6,  W7)
        CHUNK(2, W8,  W9,  W10, W11)
        CHUNK(3, W12, W13, W14, W15)
        CHUNK(4, W16, W17, W18, W19)
        CHUNK(5, W20, W21, W22, W23)
        CHUNK(6, W24, W25, W26, W27)
        CHUNK(7, W28, W29, W30, W31)
#undef CHUNK

        gates_part[half * 512 + j] = (a0 + a1) + (a2 + a3);
        __syncthreads();

        if (tid < HDIM) {
            float gi = sigm(gates_part[tid]           + gates_part[tid + 512]);
            float gf = sigm(gates_part[tid + 128]     + gates_part[tid + 640]);
            float gg = tanh_fast(gates_part[tid + 256] + gates_part[tid + 768]);
            float go = sigm(gates_part[tid + 384]     + gates_part[tid + 896]);
            c = fmaf(gf, c, gi * gg);
            float h = go * tanh_fast(c);
            *hw = (_Float16)h;

            float p = tanh_fast(h) * wout;
            #pragma unroll
            for (int off = 32; off > 0; off >>= 1)
                p += __shfl_xor(p, off, 64);
            if ((tid & 63) == 0) red_sh[tid >> 6] = p;
        }
        __syncthreads();

        if (tid == 0) out[t] = red_sh[0] + red_sh[1] + bout;
        xcur = xnext;
    }
}

extern "C" void kernel_launch(void* const* d_in, const int* in_sizes, int n_in,
                              void* d_out, int out_size, void* d_ws, size_t ws_size,
                              hipStream_t stream) {
    const float* x     = (const float*)d_in[0];
    const float* h0    = (const float*)d_in[1];
    const float* c0    = (const float*)d_in[2];
    const float* W_ih  = (const float*)d_in[3];
    const float* W_hh  = (const float*)d_in[4];
    const float* b_ih  = (const float*)d_in[5];
    const float* b_hh  = (const float*)d_in[6];
    const float* W_out = (const float*)d_in[7];
    const float* b_out = (const float*)d_in[8];

    const size_t need = (size_t)S_LEN * HDIM * sizeof(_Float16);  // 16 MiB
    if (ws_size >= need) {
        _Float16* h_hist = (_Float16*)d_ws;
        lstm_seq_h<<<dim3(1), dim3(NTHR), 0, stream>>>(
            x, h0, c0, W_ih, W_hh, b_ih, b_hh, h_hist);
        out_proj<<<dim3(1024), dim3(256), 0, stream>>>(
            h_hist, W_out, b_out, (float*)d_out);
    } else {
        lstm_seq_full<<<dim3(1), dim3(NTHR), 0, stream>>>(
            x, h0, c0, W_ih, W_hh, b_ih, b_hh, W_out, b_out, (float*)d_out);
    }
}

// Round 7
// 44196.295 us; speedup vs baseline: 2.5287x; 1.0396x over previous
//
#include <hip/hip_runtime.h>

#define S_LEN 65536
#define HDIM 128

typedef _Float16 half2_t __attribute__((ext_vector_type(2)));
typedef _Float16 half8_t __attribute__((ext_vector_type(8)));
typedef float f32x4 __attribute__((ext_vector_type(4)));

__device__ __forceinline__ float sigm(float x) {
    return 1.0f / (1.0f + __expf(-x));
}
__device__ __forceinline__ float tanh_fast(float x) {
    return 2.0f / (1.0f + __expf(-2.0f * x)) - 1.0f;
}
__device__ __forceinline__ float dot2(half2_t a, half2_t b, float c) {
#if __has_builtin(__builtin_amdgcn_fdot2)
    return __builtin_amdgcn_fdot2(a, b, c, false);
#else
    return fmaf((float)a.x, (float)b.x, fmaf((float)a.y, (float)b.y, c));
#endif
}

// ================= Kernel 1: MFMA recurrence =================
// R6 post-mortem: plateau is LDS *return bandwidth* -- the dot formulation
// delivers 512x128x2B = 128 KiB/step to lanes (~1540 cyc at 85 B/cyc, m134).
// MFMA formulation: gates(512) = W_hh(512x128) . h, split into 32 row-tiles
// x 4 k-chunks of mfma_f32_16x16x32_f16 across 8 waves (4 tiles/wave).
// h enters via B-fragments: only column 0 is used -> only lanes {0,16,32,48}
// need real data -> exec-masked ds_read_b128 delivers 64 B/instr, total
// ~2 KiB/step. W_hh lives in 64 pinned A-fragment VGPRs per thread
// (waves_per_eu(2,2): 8 waves on the CU -> 256-VGPR budget, no spill).
// Layouts (guide-verified): A[m=lane&15][k=(lane>>4)*8+j]; B mirrored
// (n=lane&15, k=(lane>>4)*8+j); D col=lane&15, row=(lane>>4)*4+reg.
__global__ __launch_bounds__(512)
__attribute__((amdgpu_waves_per_eu(2, 2)))
void lstm_seq_mfma(const float* __restrict__ x,
                   const float* __restrict__ h0,
                   const float* __restrict__ c0,
                   const float* __restrict__ W_ih,
                   const float* __restrict__ W_hh,
                   const float* __restrict__ b_ih,
                   const float* __restrict__ b_hh,
                   _Float16* __restrict__ h_hist)
{
    __shared__ __align__(16) _Float16 h_sh16[HDIM];   // h_t, packed f16
    __shared__ __align__(16) float gates_sh[4 * HDIM];

    const int tid  = threadIdx.x;       // 0..511, 8 waves
    const int lane = tid & 63;
    const int w    = tid >> 6;          // wave id 0..7: rows [w*64, w*64+64)
    const int m    = lane & 15;         // A-fragment row within tile
    const int quad = lane >> 4;         // 0..3

    // ---- A fragments: 4 row-tiles x 4 k-chunks, f32->f16, asm-pinned ----
#define LOAD_AF(i, q) \
    half8_t af_##i##_##q; { \
        const float* s_ = W_hh + (size_t)(w * 64 + 16 * (i) + m) * HDIM \
                               + 32 * (q) + 8 * quad; \
        af_##i##_##q = (half8_t){ \
            (_Float16)s_[0], (_Float16)s_[1], (_Float16)s_[2], (_Float16)s_[3], \
            (_Float16)s_[4], (_Float16)s_[5], (_Float16)s_[6], (_Float16)s_[7] }; \
        asm volatile("" : "+v"(af_##i##_##q)); }
    LOAD_AF(0, 0) LOAD_AF(0, 1) LOAD_AF(0, 2) LOAD_AF(0, 3)
    LOAD_AF(1, 0) LOAD_AF(1, 1) LOAD_AF(1, 2) LOAD_AF(1, 3)
    LOAD_AF(2, 0) LOAD_AF(2, 1) LOAD_AF(2, 2) LOAD_AF(2, 3)
    LOAD_AF(3, 0) LOAD_AF(3, 1) LOAD_AF(3, 2) LOAD_AF(3, 3)
#undef LOAD_AF

    // ---- Phase-B per-thread state (waves 0,1 only): x-proj + bias + c ----
    float wi0x = 0.f, wi0y = 0.f, bs0 = 0.f;
    float wi1x = 0.f, wi1y = 0.f, bs1 = 0.f;
    float wi2x = 0.f, wi2y = 0.f, bs2 = 0.f;
    float wi3x = 0.f, wi3y = 0.f, bs3 = 0.f;
    float c = 0.0f;
    if (tid < HDIM) {
        wi0x = W_ih[2 * tid];            wi0y = W_ih[2 * tid + 1];
        wi1x = W_ih[2 * (tid + 128)];    wi1y = W_ih[2 * (tid + 128) + 1];
        wi2x = W_ih[2 * (tid + 256)];    wi2y = W_ih[2 * (tid + 256) + 1];
        wi3x = W_ih[2 * (tid + 384)];    wi3y = W_ih[2 * (tid + 384) + 1];
        bs0 = b_ih[tid]       + b_hh[tid];
        bs1 = b_ih[tid + 128] + b_hh[tid + 128];
        bs2 = b_ih[tid + 256] + b_hh[tid + 256];
        bs3 = b_ih[tid + 384] + b_hh[tid + 384];
        c = c0[tid];
        h_sh16[tid] = (_Float16)h0[tid];
    }
    __syncthreads();

    const float2* xp = (const float2*)x;
    float2 xcur = {0.f, 0.f}, xnext = {0.f, 0.f};
    if (tid < HDIM) xcur = xp[0];

    half8_t bf0 = (half8_t){0,0,0,0,0,0,0,0};
    half8_t bf1 = bf0, bf2 = bf0, bf3 = bf0;

    #pragma unroll 1
    for (int t = 0; t < S_LEN; ++t) {
        // ---- Phase A: gates = W_hh . h via MFMA ----
        if (m == 0) {  // lanes 0,16,32,48: load B-fragment (col 0 = h)
            const half8_t* hb = (const half8_t*)h_sh16;  // 16 chunks of 8 f16
            bf0 = hb[quad];        // k = 8*quad + j          (chunk 0)
            bf1 = hb[4 + quad];    // k = 32 + 8*quad + j
            bf2 = hb[8 + quad];    // k = 64 + 8*quad + j
            bf3 = hb[12 + quad];   // k = 96 + 8*quad + j
        }
        f32x4 acc0 = {0.f, 0.f, 0.f, 0.f};
        f32x4 acc1 = {0.f, 0.f, 0.f, 0.f};
        f32x4 acc2 = {0.f, 0.f, 0.f, 0.f};
        f32x4 acc3 = {0.f, 0.f, 0.f, 0.f};
#define MFMA_TILE(i) \
        acc##i = __builtin_amdgcn_mfma_f32_16x16x32_f16(af_##i##_0, bf0, acc##i, 0, 0, 0); \
        acc##i = __builtin_amdgcn_mfma_f32_16x16x32_f16(af_##i##_1, bf1, acc##i, 0, 0, 0); \
        acc##i = __builtin_amdgcn_mfma_f32_16x16x32_f16(af_##i##_2, bf2, acc##i, 0, 0, 0); \
        acc##i = __builtin_amdgcn_mfma_f32_16x16x32_f16(af_##i##_3, bf3, acc##i, 0, 0, 0);
        MFMA_TILE(0) MFMA_TILE(1) MFMA_TILE(2) MFMA_TILE(3)
#undef MFMA_TILE
        if (m == 0) {  // col-0 lanes hold gates: reg r = row 16*i + 4*quad + r
            f32x4* gp = (f32x4*)gates_sh + w * 16 + quad;
            gp[0]  = acc0;   // tile 0: rows w*64 + 4*quad + {0..3}
            gp[4]  = acc1;   // tile 1: +16
            gp[8]  = acc2;   // tile 2: +32
            gp[12] = acc3;   // tile 3: +48
        }

        if (tid < HDIM) {
            const int tn = (t + 1 < S_LEN) ? (t + 1) : (S_LEN - 1);
            xnext = xp[tn];   // prefetch next x (waves 0-1 only)
        }
        __syncthreads();  // barrier 1: gates complete

        // ---- Phase B: activations + state update (waves 0,1) ----
        if (tid < HDIM) {
            float gi = sigm(gates_sh[tid]
                            + fmaf(wi0x, xcur.x, fmaf(wi0y, xcur.y, bs0)));
            float gf = sigm(gates_sh[tid + 128]
                            + fmaf(wi1x, xcur.x, fmaf(wi1y, xcur.y, bs1)));
            float gg = tanh_fast(gates_sh[tid + 256]
                            + fmaf(wi2x, xcur.x, fmaf(wi2y, xcur.y, bs2)));
            float go = sigm(gates_sh[tid + 384]
                            + fmaf(wi3x, xcur.x, fmaf(wi3y, xcur.y, bs3)));
            c = fmaf(gf, c, gi * gg);
            float h = go * tanh_fast(c);
            _Float16 hf = (_Float16)h;
            h_sh16[tid] = hf;                  // feeds next step's B-frags
            h_hist[t * HDIM + tid] = hf;       // consumed by out_proj
            xcur = xnext;
        }
        __syncthreads();  // barrier 2: h_t visible
    }
}

// ================= Kernel 2: out[t] = tanh(h_t).W_out + b =================
__global__ __launch_bounds__(256)
void out_proj(const _Float16* __restrict__ h_hist,
              const float* __restrict__ W_out,
              const float* __restrict__ b_out,
              float* __restrict__ out)
{
    const int lane  = threadIdx.x & 63;
    const int gwave = (blockIdx.x * 256 + threadIdx.x) >> 6;
    const int nwave = (gridDim.x * 256) >> 6;

    const float wo0 = W_out[2 * lane + 0];
    const float wo1 = W_out[2 * lane + 1];
    const float bout = b_out[0];

    for (int t = gwave; t < S_LEN; t += nwave) {
        half2_t hv = ((const half2_t*)(h_hist + t * HDIM))[lane];
        float p = tanh_fast((float)hv.x) * wo0 + tanh_fast((float)hv.y) * wo1;
        #pragma unroll
        for (int off = 32; off > 0; off >>= 1)
            p += __shfl_xor(p, off, 64);
        if (lane == 0) out[t] = p + bout;
    }
}

// ================= Fallback: fused single kernel (ws too small) ===========
#define H_HI_OFF 144
__global__ __launch_bounds__(1024)
__attribute__((amdgpu_waves_per_eu(4, 4)))
void lstm_seq_full(const float* __restrict__ x,
                   const float* __restrict__ h0,
                   const float* __restrict__ c0,
                   const float* __restrict__ W_ih,
                   const float* __restrict__ W_hh,
                   const float* __restrict__ b_ih,
                   const float* __restrict__ b_hh,
                   const float* __restrict__ W_out,
                   const float* __restrict__ b_out,
                   float* __restrict__ out)
{
    __shared__ __align__(16) unsigned char h_raw[2 * H_HI_OFF];
    __shared__ float gates_part[2 * 512];
    __shared__ float red_sh[2];

    const int tid  = threadIdx.x;
    const int j    = tid >> 1;
    const int half = tid & 1;

    const float2* wr2 = (const float2*)(W_hh + j * HDIM + half * 64);
#define WDEF(i) half2_t W##i; { float2 t = wr2[i]; \
        W##i.x = (_Float16)t.x; W##i.y = (_Float16)t.y; } \
        asm volatile("" : "+v"(W##i));
    WDEF(0)  WDEF(1)  WDEF(2)  WDEF(3)  WDEF(4)  WDEF(5)  WDEF(6)  WDEF(7)
    WDEF(8)  WDEF(9)  WDEF(10) WDEF(11) WDEF(12) WDEF(13) WDEF(14) WDEF(15)
    WDEF(16) WDEF(17) WDEF(18) WDEF(19) WDEF(20) WDEF(21) WDEF(22) WDEF(23)
    WDEF(24) WDEF(25) WDEF(26) WDEF(27) WDEF(28) WDEF(29) WDEF(30) WDEF(31)
#undef WDEF

    float wih0 = 0.0f, wih1 = 0.0f, bias = 0.0f;
    if (half == 0) {
        wih0 = W_ih[2 * j + 0];
        wih1 = W_ih[2 * j + 1];
        bias = b_ih[j] + b_hh[j];
    }

    float c = 0.0f, wout = 0.0f;
    _Float16* hw = (_Float16*)(h_raw + ((tid < 64) ? 2 * tid
                                                   : H_HI_OFF + 2 * (tid - 64)));
    if (tid < HDIM) {
        c = c0[tid];
        wout = W_out[tid];
        *hw = (_Float16)h0[tid];
    }
    const float bout = b_out[0];
    __syncthreads();

    const float2* xp = (const float2*)x;
    float2 xcur = xp[0];
    const half8_t* hp = (const half8_t*)(h_raw + half * H_HI_OFF);

    #pragma unroll 1
    for (int t = 0; t < S_LEN; ++t) {
        const int tn = (t + 1 < S_LEN) ? (t + 1) : (S_LEN - 1);
        float2 xnext = xp[tn];

        float a0 = fmaf(wih0, xcur.x, fmaf(wih1, xcur.y, bias));
        float a1 = 0.0f, a2 = 0.0f, a3 = 0.0f;

#define CHUNK(cc, w0_, w1_, w2_, w3_) {                         \
        half8_t hv = hp[cc];                                    \
        half2_t p0 = { hv[0], hv[1] };                          \
        half2_t p1 = { hv[2], hv[3] };                          \
        half2_t p2 = { hv[4], hv[5] };                          \
        half2_t p3 = { hv[6], hv[7] };                          \
        a0 = dot2(w0_, p0, a0);                                 \
        a1 = dot2(w1_, p1, a1);                                 \
        a2 = dot2(w2_, p2, a2);                                 \
        a3 = dot2(w3_, p3, a3); }
        CHUNK(0, W0,  W1,  W2,  W3)
        CHUNK(1, W4,  W5,  W6,  W7)
        CHUNK(2, W8,  W9,  W10, W11)
        CHUNK(3, W12, W13, W14, W15)
        CHUNK(4, W16, W17, W18, W19)
        CHUNK(5, W20, W21, W22, W23)
        CHUNK(6, W24, W25, W26, W27)
        CHUNK(7, W28, W29, W30, W31)
#undef CHUNK

        gates_part[half * 512 + j] = (a0 + a1) + (a2 + a3);
        __syncthreads();

        if (tid < HDIM) {
            float gi = sigm(gates_part[tid]            + gates_part[tid + 512]);
            float gf = sigm(gates_part[tid + 128]      + gates_part[tid + 640]);
            float gg = tanh_fast(gates_part[tid + 256] + gates_part[tid + 768]);
            float go = sigm(gates_part[tid + 384]      + gates_part[tid + 896]);
            c = fmaf(gf, c, gi * gg);
            float h = go * tanh_fast(c);
            *hw = (_Float16)h;

            float p = tanh_fast(h) * wout;
            #pragma unroll
            for (int off = 32; off > 0; off >>= 1)
                p += __shfl_xor(p, off, 64);
            if ((tid & 63) == 0) red_sh[tid >> 6] = p;
        }
        __syncthreads();

        if (tid == 0) out[t] = red_sh[0] + red_sh[1] + bout;
        xcur = xnext;
    }
}

extern "C" void kernel_launch(void* const* d_in, const int* in_sizes, int n_in,
                              void* d_out, int out_size, void* d_ws, size_t ws_size,
                              hipStream_t stream) {
    const float* x     = (const float*)d_in[0];
    const float* h0    = (const float*)d_in[1];
    const float* c0    = (const float*)d_in[2];
    const float* W_ih  = (const float*)d_in[3];
    const float* W_hh  = (const float*)d_in[4];
    const float* b_ih  = (const float*)d_in[5];
    const float* b_hh  = (const float*)d_in[6];
    const float* W_out = (const float*)d_in[7];
    const float* b_out = (const float*)d_in[8];

    const size_t need = (size_t)S_LEN * HDIM * sizeof(_Float16);  // 16 MiB
    if (ws_size >= need) {
        _Float16* h_hist = (_Float16*)d_ws;
        lstm_seq_mfma<<<dim3(1), dim3(512), 0, stream>>>(
            x, h0, c0, W_ih, W_hh, b_ih, b_hh, h_hist);
        out_proj<<<dim3(1024), dim3(256), 0, stream>>>(
            h_hist, W_out, b_out, (float*)d_out);
    } else {
        lstm_seq_full<<<dim3(1), dim3(1024), 0, stream>>>(
            x, h0, c0, W_ih, W_hh, b_ih, b_hh, W_out, b_out, (float*)d_out);
    }
}